// Round 1
// baseline (136.822 us; speedup 1.0000x reference)
//
#include <hip/hip_runtime.h>
#include <stdint.h>

// LocallyConnected1d: out[b,c,o] = (1/8) * sum_{i<64,k<8} x[b,i,4o+k] * w[c,i,o,k]
// B=128, CIN=64, COUT=64, OUT_DIM=256, K=8, S=4, L=1028. fp32 in/out.
// Strategy: 256 blocks (one o each, XCD-swizzled), 256 threads.
// Per block: full 128x64 GEMM with Kdim=512, CIN chunked by 16 (K-chunk=128),
// fp32->bf16 convert into LDS, mfma_f32_16x16x32_bf16, 2x4 tiles per wave.

#define B_    128
#define CIN_  64
#define COUT_ 64
#define OD_   256
#define K_    8
#define S_    4
#define L_    1028

#define CI_CHUNK 16
#define KC  (CI_CHUNK * K_)      // 128 k-elems per chunk
#define LDK (KC + 8)             // +8 shorts (16B) pad -> balanced b128 banks
#define NCHUNK (CIN_ / CI_CHUNK) // 4

typedef __attribute__((ext_vector_type(8))) short bf16x8;   // 8 bf16 in 4 VGPRs
typedef __attribute__((ext_vector_type(4))) float floatx4;  // MFMA accumulator

__device__ __forceinline__ unsigned short f32_to_bf16(float f) {
    union { float f; uint32_t u; } v; v.f = f;
    uint32_t u = v.u;
    // round-to-nearest-even (inputs are finite random normals; no NaN path needed)
    u += 0x7FFFu + ((u >> 16) & 1u);
    return (unsigned short)(u >> 16);
}

__global__ __launch_bounds__(256, 1)
void lc1d_mfma_kernel(const float* __restrict__ x,
                      const float* __restrict__ w,
                      float* __restrict__ out) {
    __shared__ unsigned short Ax[B_ * LDK];    // 128*136*2 = 34816 B
    __shared__ unsigned short Bw[COUT_ * LDK]; //  64*136*2 = 17408 B

    const int tid  = threadIdx.x;
    // XCD swizzle: round-robin block->XCD assumed; give each XCD 32 consecutive o's
    // so overlapping x windows (K/S=2) and o-adjacent w lines share that XCD's L2.
    const int o    = ((blockIdx.x & 7) << 5) + (blockIdx.x >> 3);

    const int wave = tid >> 6;
    const int lane = tid & 63;
    const int quad = lane >> 4;
    const int m16  = lane & 15;

    floatx4 acc[2][4];
    #pragma unroll
    for (int i = 0; i < 2; ++i)
        #pragma unroll
        for (int j = 0; j < 4; ++j)
            acc[i][j] = (floatx4){0.f, 0.f, 0.f, 0.f};

    for (int ch = 0; ch < NCHUNK; ++ch) {
        const int ci0 = ch * CI_CHUNK;

        // ---- stage x chunk: 128 b x 16 i x 8 k  = 4096 float4 units ----
        #pragma unroll
        for (int it = 0; it < 16; ++it) {
            const int u    = it * 256 + tid;
            const int half = u & 1;          // which float4 of the 8-float run
            const int pair = u >> 1;         // (b, i_local)
            const int iL   = pair & 15;
            const int b    = pair >> 4;
            const float4 v = *(const float4*)(x + ((b * CIN_ + ci0 + iL) * L_ + o * S_ + half * 4));
            ushort4 sv = make_ushort4(f32_to_bf16(v.x), f32_to_bf16(v.y),
                                      f32_to_bf16(v.z), f32_to_bf16(v.w));
            *(ushort4*)&Ax[b * LDK + iL * 8 + half * 4] = sv;  // kk = i*8 + k
        }
        // ---- stage w chunk: 64 c x 16 i x 8 k = 2048 float4 units ----
        #pragma unroll
        for (int it = 0; it < 8; ++it) {
            const int u    = it * 256 + tid;
            const int half = u & 1;
            const int pair = u >> 1;
            const int iL   = pair & 15;
            const int c    = pair >> 4;
            const float4 v = *(const float4*)(w + (((c * CIN_ + ci0 + iL) * OD_ + o) * K_ + half * 4));
            ushort4 sv = make_ushort4(f32_to_bf16(v.x), f32_to_bf16(v.y),
                                      f32_to_bf16(v.z), f32_to_bf16(v.w));
            *(ushort4*)&Bw[c * LDK + iL * 8 + half * 4] = sv;  // same kk ordering
        }
        __syncthreads();

        // ---- compute: K-chunk 128 = 4 MFMA k-steps of 32 ----
        #pragma unroll
        for (int kt = 0; kt < 4; ++kt) {
            bf16x8 afrag[2], bfrag[4];
            #pragma unroll
            for (int rt = 0; rt < 2; ++rt) {
                const int row = (wave * 2 + rt) * 16 + m16;          // m = lane&15
                afrag[rt] = *(const bf16x8*)&Ax[row * LDK + kt * 32 + quad * 8];
            }
            #pragma unroll
            for (int ct = 0; ct < 4; ++ct) {
                const int row = ct * 16 + m16;                        // n = lane&15
                bfrag[ct] = *(const bf16x8*)&Bw[row * LDK + kt * 32 + quad * 8];
            }
            #pragma unroll
            for (int rt = 0; rt < 2; ++rt)
                #pragma unroll
                for (int ct = 0; ct < 4; ++ct)
                    acc[rt][ct] = __builtin_amdgcn_mfma_f32_16x16x32_bf16(
                        afrag[rt], bfrag[ct], acc[rt][ct], 0, 0, 0);
        }
        __syncthreads();  // protect LDS before next chunk's staging
    }

    // ---- epilogue: D layout col=lane&15 (c), row=quad*4+reg (b); scale 1/sqrt(64) ----
    #pragma unroll
    for (int rt = 0; rt < 2; ++rt) {
        #pragma unroll
        for (int ct = 0; ct < 4; ++ct) {
            #pragma unroll
            for (int r = 0; r < 4; ++r) {
                const int b = (wave * 2 + rt) * 16 + quad * 4 + r;
                const int c = ct * 16 + m16;
                out[(b * COUT_ + c) * OD_ + o] = acc[rt][ct][r] * 0.125f;
            }
        }
    }
}

extern "C" void kernel_launch(void* const* d_in, const int* in_sizes, int n_in,
                              void* d_out, int out_size, void* d_ws, size_t ws_size,
                              hipStream_t stream) {
    const float* x = (const float*)d_in[0];   // (128, 64, 1028)
    const float* w = (const float*)d_in[1];   // (1, 64, 64, 256, 8)
    float* out = (float*)d_out;               // (128, 64, 256)
    hipLaunchKernelGGL(lc1d_mfma_kernel, dim3(256), dim3(256), 0, stream, x, w, out);
}